// Round 4
// baseline (715.686 us; speedup 1.0000x reference)
//
#include <hip/hip_runtime.h>
#include <math.h>
#include <stdint.h>

#define NANCH 49104
#define NCLS 80
#define KSEL 100
#define NFLAT (NCLS * KSEL)
#define PREDC 84
#define NB 8
#define ECAP 128
#define CAP 3072
#define TOTF4 (NB * NANCH * (PREDC / 4))   // 8,249,472 float4s
// logit(0.9): candidates are scores > 0.9; per-class top-100 threshold ~0.947 here
#define THRL 2.1972246f

struct DimsTable { float d[5][9][2]; };
struct KT { uint32_t key; int tie; };

__device__ __forceinline__ uint32_t f2key(float f) {
    uint32_t u = __float_as_uint(f);
    return u ^ (uint32_t((int32_t)u >> 31) | 0x80000000u);
}
__device__ __forceinline__ float key2f(uint32_t k) {
    uint32_t u = (k & 0x80000000u) ? (k ^ 0x80000000u) : ~k;
    return __uint_as_float(u);
}
__device__ __forceinline__ float sigm(float x) { return 1.0f / (1.0f + expf(-x)); }

__device__ __forceinline__ void decode_box(const float4 pv, int n,
                                           const DimsTable& dt, float box[4]) {
    int lev, base, fw, stride;
    if (n < 36864)      { lev = 0; base = 0;     fw = 64; stride = 8;   }
    else if (n < 46080) { lev = 1; base = 36864; fw = 32; stride = 16;  }
    else if (n < 48384) { lev = 2; base = 46080; fw = 16; stride = 32;  }
    else if (n < 48960) { lev = 3; base = 48384; fw = 8;  stride = 64;  }
    else                { lev = 4; base = 48960; fw = 4;  stride = 128; }
    int i = n - base;
    int k = i % 9;
    int cell = i / 9;
    int xq = cell % fw, yq = cell / fw;
    float cx = ((float)xq + 0.5f) * (float)stride;
    float cy = ((float)yq + 0.5f) * (float)stride;
    float aw = dt.d[lev][k][0];
    float ah = dt.d[lev][k][1];
    float tx = __fmul_rn(pv.x, 0.1f);
    float ty = __fmul_rn(pv.y, 0.1f);
    float tw = __fmul_rn(pv.z, 0.2f);
    float th = __fmul_rn(pv.w, 0.2f);
    float px = __fadd_rn(__fmul_rn(tx, aw), cx);
    float py = __fadd_rn(__fmul_rn(ty, ah), cy);
    float pw = __fmul_rn(expf(tw), aw);
    float ph = __fmul_rn(expf(th), ah);
    float hw = __fmul_rn(pw, 0.5f);
    float hh = __fmul_rn(ph, 0.5f);
    box[0] = __fsub_rn(px, hw);
    box[1] = __fsub_rn(py, hh);
    box[2] = __fadd_rn(px, hw);
    box[3] = __fadd_rn(py, hh);
}

struct SelSh {
    int hist[4][2048];
    int suffix[256];
    uint32_t candKey[KSEL];
    int candIdx[KSEL];
    uint32_t eIdx[ECAP];
    uint32_t sKey[KSEL];
    int sIdx[KSEL];
    int cntG, cntE, krem, newkrem, digit, flast, rmin;
    uint32_t prefix, thrKey;
};

// Exact top-min(K,N) by (key desc, tie asc); fills sh.sKey/sIdx sorted. 256 thr.
template <typename G>
__device__ int block_select(G get, int N, int K, SelSh& sh) {
    const int tid = threadIdx.x;
    const int wid = tid >> 6;
    int Ksel = (N < K) ? N : K;
    if (Ksel <= 0) return 0;

    if (N <= K) {                     // take everything, just sort
        if (tid < N) { KT e = get(tid); sh.candKey[tid] = e.key; sh.candIdx[tid] = e.tie; }
        __syncthreads();
        if (tid < N) {
            uint32_t mk = sh.candKey[tid]; int mi = sh.candIdx[tid];
            int rank = 0;
            for (int j = 0; j < N; ++j) {
                uint32_t kj = sh.candKey[j]; int ij = sh.candIdx[j];
                rank += (kj > mk) || (kj == mk && ij < mi);
            }
            sh.sKey[rank] = mk; sh.sIdx[rank] = mi;
        }
        __syncthreads();
        return Ksel;
    }

    if (tid == 0) { sh.krem = K; sh.prefix = 0; }
    for (int pass = 0; pass < 3; ++pass) {
        const int bins   = (pass == 2) ? 1024 : 2048;
        const int dshift = (pass == 0) ? 21 : (pass == 1 ? 10 : 0);
        const int fshift = (pass == 1) ? 21 : 10;
        const int dmask  = bins - 1;
        const bool multi = (pass == 0);
        if (multi) { for (int j = tid; j < 4 * 2048; j += 256) ((int*)sh.hist)[j] = 0; }
        else       { for (int j = tid; j < bins; j += 256) sh.hist[0][j] = 0; }
        __syncthreads();
        const uint32_t pref = sh.prefix;
        for (int i = tid; i < N; i += 256) {
            uint32_t key = get(i).key;
            if (pass == 0) {
                atomicAdd(&sh.hist[wid][(key >> dshift) & dmask], 1);
            } else if ((key >> fshift) == pref) {
                atomicAdd(&sh.hist[0][(key >> dshift) & dmask], 1);
            }
        }
        __syncthreads();
        if (multi) {
            for (int j = tid; j < bins; j += 256)
                sh.hist[0][j] += sh.hist[1][j] + sh.hist[2][j] + sh.hist[3][j];
            __syncthreads();
        }
        const int cpb = bins / 256;
        const int base = tid * cpb;
        int lsum = 0;
        for (int j = 0; j < cpb; ++j) lsum += sh.hist[0][base + j];
        // parallel suffix sum: suffix[tid] = sum_{t>=tid} lsum_t  (Hillis-Steele)
        sh.suffix[tid] = lsum;
        __syncthreads();
        for (int off = 1; off < 256; off <<= 1) {
            int v = (tid + off < 256) ? sh.suffix[tid + off] : 0;
            __syncthreads();
            sh.suffix[tid] += v;
            __syncthreads();
        }
        {
            int cum = sh.suffix[tid] - lsum;   // sum over bins above this thread's range
            const int krem = sh.krem;
            for (int j = cpb - 1; j >= 0; --j) {
                int cnt = sh.hist[0][base + j];
                if (cnt > 0 && cum < krem && cum + cnt >= krem) {
                    sh.digit = base + j;
                    sh.newkrem = krem - cum;
                }
                cum += cnt;
            }
        }
        __syncthreads();
        if (tid == 0) {
            sh.krem = sh.newkrem;
            if (pass == 0)      sh.prefix = (uint32_t)sh.digit;
            else if (pass == 1) sh.prefix = (sh.prefix << 11) | (uint32_t)sh.digit;
            else                sh.thrKey = (sh.prefix << 10) | (uint32_t)sh.digit;
        }
        __syncthreads();
    }

    if (tid == 0) { sh.cntG = 0; sh.cntE = 0; }
    __syncthreads();
    const uint32_t thr = sh.thrKey;
    for (int i = tid; i < N; i += 256) {
        KT e = get(i);
        if (e.key > thr) {
            int g = atomicAdd(&sh.cntG, 1);
            sh.candKey[g] = e.key; sh.candIdx[g] = e.tie;
        } else if (e.key == thr) {
            int idx = atomicAdd(&sh.cntE, 1);
            if (idx < ECAP) sh.eIdx[idx] = (uint32_t)e.tie;
        }
    }
    __syncthreads();
    const int need = sh.krem;
    const int nG = K - need;
    if (sh.cntE <= ECAP) {
        const int ce = sh.cntE;
        if (tid < ce) {
            uint32_t my = sh.eIdx[tid];
            int rank = 0;
            for (int j = 0; j < ce; ++j) rank += (sh.eIdx[j] < my);
            if (rank < need) { sh.candKey[nG + rank] = thr; sh.candIdx[nG + rank] = (int)my; }
        }
    } else {
        if (tid == 0) sh.flast = -1;
        __syncthreads();
        for (int t = 0; t < need; ++t) {
            if (tid == 0) sh.rmin = 0x7FFFFFFF;
            __syncthreads();
            const int fl = sh.flast;
            int lmin = 0x7FFFFFFF;
            for (int i = tid; i < N; i += 256) {
                KT e = get(i);
                if (e.key == thr && e.tie > fl) lmin = min(lmin, e.tie);
            }
            atomicMin(&sh.rmin, lmin);
            __syncthreads();
            if (tid == 0) { sh.candKey[nG + t] = thr; sh.candIdx[nG + t] = sh.rmin; sh.flast = sh.rmin; }
            __syncthreads();
        }
    }
    __syncthreads();
    if (tid < K) {
        uint32_t mk = sh.candKey[tid]; int mi = sh.candIdx[tid];
        int rank = 0;
        for (int j = 0; j < K; ++j) {
            uint32_t kj = sh.candKey[j]; int ij = sh.candIdx[j];
            rank += (kj > mk) || (kj == mk && ij < mi);
        }
        sh.sKey[rank] = mk; sh.sIdx[rank] = mi;
    }
    __syncthreads();
    return Ksel;
}

// ---------- kernel 1: coalesced flat scan, compact candidates ----------------
__global__ __launch_bounds__(256) void cand_scan(const float4* __restrict__ predv,
                                                 uint2* __restrict__ cand,
                                                 int* __restrict__ cnt) {
    const int nt = gridDim.x * 256;
    for (int v = blockIdx.x * 256 + threadIdx.x; v < TOTF4; v += nt) {
        float4 p = predv[v];
        uint32_t q = (uint32_t)v / 21u;          // row index (global over batches)
        uint32_t j = (uint32_t)v - q * 21u;      // float4 slot within row
        if (j == 0u) continue;                   // box-coord channels
        bool p0 = p.x > THRL, p1 = p.y > THRL, p2 = p.z > THRL, p3 = p.w > THRL;
        if (!(p0 | p1 | p2 | p3)) continue;
        uint32_t b = q / (uint32_t)NANCH;
        uint32_t row = q - b * (uint32_t)NANCH;
        int cbase = ((int)j - 1) * 4;
        int bcb = (int)b * NCLS + cbase;
        float vv[4] = {p.x, p.y, p.z, p.w};
        bool pp[4] = {p0, p1, p2, p3};
#pragma unroll
        for (int k = 0; k < 4; ++k) {
            if (pp[k]) {
                int bc = bcb + k;
                float s = sigm(vv[k]);
                int slot = atomicAdd(&cnt[bc], 1);
                if (slot < CAP)
                    cand[(size_t)bc * CAP + slot] = make_uint2(f2key(s), row);
            }
        }
    }
}

// ---------- kernel 2: per-(b,c) exact top-100 + wave NMS ---------------------
__global__ __launch_bounds__(256) void nms_sel(const float* __restrict__ pred,
                                               const uint2* __restrict__ cand,
                                               const int* __restrict__ cnt,
                                               float* __restrict__ cls_boxes,
                                               uint32_t* __restrict__ posKey,
                                               uint32_t* __restrict__ posFlat,
                                               int* __restrict__ posCnt,
                                               DimsTable dt) {
    __shared__ SelSh sh;
    const int c = blockIdx.x;
    const int b = blockIdx.y;
    const int tid = threadIdx.x;
    const int bc = b * NCLS + c;
    const int n = cnt[bc];

    if (n >= KSEL && n <= CAP) {
        const uint2* src = cand + (size_t)bc * CAP;
        auto g = [src](int i) { uint2 p = src[i]; KT e; e.key = p.x; e.tie = (int)p.y; return e; };
        block_select(g, n, KSEL, sh);
    } else {
        // exact fallback: full strided scan (never taken on this data)
        const float* src = pred + (size_t)b * NANCH * PREDC + 4 + c;
        auto g = [src](int i) { KT e; e.key = f2key(sigm(src[(size_t)i * PREDC])); e.tie = i; return e; };
        block_select(g, NANCH, KSEL, sh);
    }

    if (tid < 64) {
        const int l = tid;
        uint32_t key0 = sh.sKey[l]; int n0 = sh.sIdx[l];
        float4 pv0 = reinterpret_cast<const float4*>(pred)[((size_t)b * NANCH + n0) * (PREDC / 4) + 0];
        float b0[4]; decode_box(pv0, n0, dt, b0);
        float area0 = __fmul_rn(__fsub_rn(b0[2], b0[0]), __fsub_rn(b0[3], b0[1]));
        int k0 = key2f(key0) > 0.05f;

        const bool has1 = (l + 64) < KSEL;
        uint32_t key1 = 0; int n1 = 0;
        float b1[4] = {0.f, 0.f, 0.f, 0.f}; float area1 = 0.f; int k1 = 0;
        if (has1) {
            key1 = sh.sKey[l + 64]; n1 = sh.sIdx[l + 64];
            float4 pv1 = reinterpret_cast<const float4*>(pred)[((size_t)b * NANCH + n1) * (PREDC / 4) + 0];
            decode_box(pv1, n1, dt, b1);
            area1 = __fmul_rn(__fsub_rn(b1[2], b1[0]), __fsub_rn(b1[3], b1[1]));
            k1 = key2f(key1) > 0.05f;
        }

        for (int i = 0; i < KSEL; ++i) {
            int kk; float c0, c1, c2, c3, ca;
            if (i < 64) { kk = k0; c0 = b0[0]; c1 = b0[1]; c2 = b0[2]; c3 = b0[3]; ca = area0; }
            else        { kk = k1; c0 = b1[0]; c1 = b1[1]; c2 = b1[2]; c3 = b1[3]; ca = area1; }
            const int sl = i & 63;
            int ki = __shfl(kk, sl);
            if (ki) {
                float ix0 = __shfl(c0, sl), iy0 = __shfl(c1, sl);
                float ix1 = __shfl(c2, sl), iy1 = __shfl(c3, sl);
                float ia  = __shfl(ca, sl);
                if (k0 && l > i) {
                    float x1 = fmaxf(ix0, b0[0]), y1 = fmaxf(iy0, b0[1]);
                    float x2 = fminf(ix1, b0[2]), y2 = fminf(iy1, b0[3]);
                    float iw = fmaxf(__fsub_rn(x2, x1), 0.0f);
                    float ih = fmaxf(__fsub_rn(y2, y1), 0.0f);
                    float inter = __fmul_rn(iw, ih);
                    float uni = __fsub_rn(__fadd_rn(ia, area0), inter);
                    if (__fdiv_rn(inter, fmaxf(uni, 1e-8f)) > 0.5f) k0 = 0;
                }
                if (k1 && (l + 64) > i) {
                    float x1 = fmaxf(ix0, b1[0]), y1 = fmaxf(iy0, b1[1]);
                    float x2 = fminf(ix1, b1[2]), y2 = fminf(iy1, b1[3]);
                    float iw = fmaxf(__fsub_rn(x2, x1), 0.0f);
                    float ih = fmaxf(__fsub_rn(y2, y1), 0.0f);
                    float inter = __fmul_rn(iw, ih);
                    float uni = __fsub_rn(__fadd_rn(ia, area1), inter);
                    if (__fdiv_rn(inter, fmaxf(uni, 1e-8f)) > 0.5f) k1 = 0;
                }
            }
        }

        reinterpret_cast<float4*>(cls_boxes)[(size_t)b * NFLAT + c * KSEL + l] =
            make_float4(b0[0], b0[1], b0[2], b0[3]);
        if (has1)
            reinterpret_cast<float4*>(cls_boxes)[(size_t)b * NFLAT + c * KSEL + l + 64] =
                make_float4(b1[0], b1[1], b1[2], b1[3]);

        unsigned long long m0 = __ballot(k0);
        unsigned long long m1 = __ballot(k1);
        int tot = __popcll(m0) + __popcll(m1);
        int base;
        if (l == 0) base = atomicAdd(&posCnt[b], tot);
        base = __shfl(base, 0);
        if (k0) {
            int off = __popcll(m0 & ((1ull << l) - 1));
            posKey[(size_t)b * NFLAT + base + off] = key0;
            posFlat[(size_t)b * NFLAT + base + off] = (uint32_t)(c * KSEL + l);
        }
        if (k1) {
            int off = __popcll(m0) + __popcll(m1 & ((1ull << l) - 1));
            posKey[(size_t)b * NFLAT + base + off] = key1;
            posFlat[(size_t)b * NFLAT + base + off] = (uint32_t)(c * KSEL + l + 64);
        }
    }
}

// ---------- kernel 3: per-batch final top-100 over compacted positives -------
__global__ __launch_bounds__(256) void final_sel(const float* __restrict__ cls_boxes,
                                                 const uint32_t* __restrict__ posKey,
                                                 const uint32_t* __restrict__ posFlat,
                                                 const int* __restrict__ posCnt,
                                                 float* __restrict__ out) {
    __shared__ SelSh sh;
    const int b = blockIdx.x;
    const int tid = threadIdx.x;
    int m = posCnt[b];
    if (m > NFLAT) m = NFLAT;
    const uint32_t* pk = posKey + (size_t)b * NFLAT;
    const uint32_t* pf = posFlat + (size_t)b * NFLAT;
    auto g = [pk, pf](int i) { KT e; e.key = pk[i]; e.tie = (int)pf[i]; return e; };
    int K = block_select(g, m, KSEL, sh);
    if (tid < KSEL) {
        float4 ob = make_float4(0.f, 0.f, 0.f, 0.f);
        float sv = 0.f, cv = 0.f;
        if (tid < K) {
            sv = key2f(sh.sKey[tid]);
            int flat = sh.sIdx[tid];
            ob = reinterpret_cast<const float4*>(cls_boxes)[(size_t)b * NFLAT + flat];
            cv = (float)(flat / KSEL);
        }
        reinterpret_cast<float4*>(out)[(size_t)b * KSEL + tid] = ob;
        out[NB * KSEL * 4 + b * KSEL + tid] = sv;
        out[NB * KSEL * 5 + b * KSEL + tid] = cv;
    }
    if (tid == 0) out[NB * KSEL * 6 + b] = (float)K;
}

// ---------- host launcher ----------------------------------------------------
extern "C" void kernel_launch(void* const* d_in, const int* in_sizes, int n_in,
                              void* d_out, int out_size, void* d_ws, size_t ws_size,
                              hipStream_t stream) {
    const float* pred = (const float*)d_in[1];
    float* out = (float*)d_out;

    DimsTable dt;
    const double areasd[5] = {1024.0, 4096.0, 16384.0, 65536.0, 262144.0};
    const double ratios[3] = {0.5, 1.0, 2.0};
    const double scales[3] = {1.0, pow(2.0, 1.0 / 3.0), pow(2.0, 2.0 / 3.0)};
    for (int l = 0; l < 5; ++l)
        for (int ri = 0; ri < 3; ++ri) {
            double ah = sqrt(areasd[l] / ratios[ri]);
            double aw = areasd[l] / ah;
            for (int si = 0; si < 3; ++si) {
                dt.d[l][ri * 3 + si][0] = (float)(aw * scales[si]);
                dt.d[l][ri * 3 + si][1] = (float)(ah * scales[si]);
            }
        }

    // workspace layout
    char* wsb = (char*)d_ws;
    int* cnt = (int*)wsb;                       // [640]
    int* posCnt = cnt + NB * NCLS;              // [8]
    uint2* cand = (uint2*)(wsb + 4096);         // [640][CAP]
    float* cls_boxes = (float*)((char*)cand + (size_t)NB * NCLS * CAP * 8);  // [8][8000][4]
    uint32_t* posKey = (uint32_t*)(cls_boxes + (size_t)NB * NFLAT * 4);      // [8][8000]
    uint32_t* posFlat = posKey + (size_t)NB * NFLAT;                          // [8][8000]

    (void)hipMemsetAsync(d_ws, 0, 4096, stream);

    cand_scan<<<2048, 256, 0, stream>>>(reinterpret_cast<const float4*>(pred),
                                        cand, cnt);

    dim3 gb(NCLS, NB);
    nms_sel<<<gb, 256, 0, stream>>>(pred, cand, cnt, cls_boxes, posKey, posFlat,
                                    posCnt, dt);

    final_sel<<<NB, 256, 0, stream>>>(cls_boxes, posKey, posFlat, posCnt, out);
}

// Round 5
// 164.458 us; speedup vs baseline: 4.3518x; 4.3518x over previous
//
#include <hip/hip_runtime.h>
#include <math.h>
#include <stdint.h>

#define NANCH 49104
#define NCLS 80
#define KSEL 100
#define NFLAT (NCLS * KSEL)
#define PREDC 84
#define NB 8
#define ECAP 128
#define CAP 3072
#define TOTF4 (NB * NANCH * (PREDC / 4))   // 8,249,472 float4s
#define BATF4 (NANCH * (PREDC / 4))        // 1,031,184 float4s per batch
#define NBLK 512
#define LCAP 64                             // per-class per-block LDS bucket cap
// logit(0.9): candidates are scores > 0.9; per-class top-100 threshold ~0.947 here
#define THRL 2.1972246f

struct DimsTable { float d[5][9][2]; };
struct KT { uint32_t key; int tie; };

__device__ __forceinline__ uint32_t f2key(float f) {
    uint32_t u = __float_as_uint(f);
    return u ^ (uint32_t((int32_t)u >> 31) | 0x80000000u);
}
__device__ __forceinline__ float key2f(uint32_t k) {
    uint32_t u = (k & 0x80000000u) ? (k ^ 0x80000000u) : ~k;
    return __uint_as_float(u);
}
__device__ __forceinline__ float sigm(float x) { return 1.0f / (1.0f + expf(-x)); }

__device__ __forceinline__ void decode_box(const float4 pv, int n,
                                           const DimsTable& dt, float box[4]) {
    int lev, base, fw, stride;
    if (n < 36864)      { lev = 0; base = 0;     fw = 64; stride = 8;   }
    else if (n < 46080) { lev = 1; base = 36864; fw = 32; stride = 16;  }
    else if (n < 48384) { lev = 2; base = 46080; fw = 16; stride = 32;  }
    else if (n < 48960) { lev = 3; base = 48384; fw = 8;  stride = 64;  }
    else                { lev = 4; base = 48960; fw = 4;  stride = 128; }
    int i = n - base;
    int k = i % 9;
    int cell = i / 9;
    int xq = cell % fw, yq = cell / fw;
    float cx = ((float)xq + 0.5f) * (float)stride;
    float cy = ((float)yq + 0.5f) * (float)stride;
    float aw = dt.d[lev][k][0];
    float ah = dt.d[lev][k][1];
    float tx = __fmul_rn(pv.x, 0.1f);
    float ty = __fmul_rn(pv.y, 0.1f);
    float tw = __fmul_rn(pv.z, 0.2f);
    float th = __fmul_rn(pv.w, 0.2f);
    float px = __fadd_rn(__fmul_rn(tx, aw), cx);
    float py = __fadd_rn(__fmul_rn(ty, ah), cy);
    float pw = __fmul_rn(expf(tw), aw);
    float ph = __fmul_rn(expf(th), ah);
    float hw = __fmul_rn(pw, 0.5f);
    float hh = __fmul_rn(ph, 0.5f);
    box[0] = __fsub_rn(px, hw);
    box[1] = __fsub_rn(py, hh);
    box[2] = __fadd_rn(px, hw);
    box[3] = __fadd_rn(py, hh);
}

struct SelSh {
    int hist[4][2048];
    int suffix[256];
    uint32_t candKey[KSEL];
    int candIdx[KSEL];
    uint32_t eIdx[ECAP];
    uint32_t sKey[KSEL];
    int sIdx[KSEL];
    int cntG, cntE, krem, newkrem, digit, flast, rmin;
    uint32_t prefix, thrKey;
};

// Exact top-min(K,N) by (key desc, tie asc); fills sh.sKey/sIdx sorted. 256 thr.
template <typename G>
__device__ int block_select(G get, int N, int K, SelSh& sh) {
    const int tid = threadIdx.x;
    const int wid = tid >> 6;
    int Ksel = (N < K) ? N : K;
    if (Ksel <= 0) return 0;

    if (N <= K) {                     // take everything, just sort
        if (tid < N) { KT e = get(tid); sh.candKey[tid] = e.key; sh.candIdx[tid] = e.tie; }
        __syncthreads();
        if (tid < N) {
            uint32_t mk = sh.candKey[tid]; int mi = sh.candIdx[tid];
            int rank = 0;
            for (int j = 0; j < N; ++j) {
                uint32_t kj = sh.candKey[j]; int ij = sh.candIdx[j];
                rank += (kj > mk) || (kj == mk && ij < mi);
            }
            sh.sKey[rank] = mk; sh.sIdx[rank] = mi;
        }
        __syncthreads();
        return Ksel;
    }

    if (tid == 0) { sh.krem = K; sh.prefix = 0; }
    for (int pass = 0; pass < 3; ++pass) {
        const int bins   = (pass == 2) ? 1024 : 2048;
        const int dshift = (pass == 0) ? 21 : (pass == 1 ? 10 : 0);
        const int fshift = (pass == 1) ? 21 : 10;
        const int dmask  = bins - 1;
        const bool multi = (pass == 0);
        if (multi) { for (int j = tid; j < 4 * 2048; j += 256) ((int*)sh.hist)[j] = 0; }
        else       { for (int j = tid; j < bins; j += 256) sh.hist[0][j] = 0; }
        __syncthreads();
        const uint32_t pref = sh.prefix;
        for (int i = tid; i < N; i += 256) {
            uint32_t key = get(i).key;
            if (pass == 0) {
                atomicAdd(&sh.hist[wid][(key >> dshift) & dmask], 1);
            } else if ((key >> fshift) == pref) {
                atomicAdd(&sh.hist[0][(key >> dshift) & dmask], 1);
            }
        }
        __syncthreads();
        if (multi) {
            for (int j = tid; j < bins; j += 256)
                sh.hist[0][j] += sh.hist[1][j] + sh.hist[2][j] + sh.hist[3][j];
            __syncthreads();
        }
        const int cpb = bins / 256;
        const int base = tid * cpb;
        int lsum = 0;
        for (int j = 0; j < cpb; ++j) lsum += sh.hist[0][base + j];
        // parallel suffix sum (Hillis-Steele)
        sh.suffix[tid] = lsum;
        __syncthreads();
        for (int off = 1; off < 256; off <<= 1) {
            int v = (tid + off < 256) ? sh.suffix[tid + off] : 0;
            __syncthreads();
            sh.suffix[tid] += v;
            __syncthreads();
        }
        {
            int cum = sh.suffix[tid] - lsum;
            const int krem = sh.krem;
            for (int j = cpb - 1; j >= 0; --j) {
                int cnt = sh.hist[0][base + j];
                if (cnt > 0 && cum < krem && cum + cnt >= krem) {
                    sh.digit = base + j;
                    sh.newkrem = krem - cum;
                }
                cum += cnt;
            }
        }
        __syncthreads();
        if (tid == 0) {
            sh.krem = sh.newkrem;
            if (pass == 0)      sh.prefix = (uint32_t)sh.digit;
            else if (pass == 1) sh.prefix = (sh.prefix << 11) | (uint32_t)sh.digit;
            else                sh.thrKey = (sh.prefix << 10) | (uint32_t)sh.digit;
        }
        __syncthreads();
    }

    if (tid == 0) { sh.cntG = 0; sh.cntE = 0; }
    __syncthreads();
    const uint32_t thr = sh.thrKey;
    for (int i = tid; i < N; i += 256) {
        KT e = get(i);
        if (e.key > thr) {
            int g = atomicAdd(&sh.cntG, 1);
            sh.candKey[g] = e.key; sh.candIdx[g] = e.tie;
        } else if (e.key == thr) {
            int idx = atomicAdd(&sh.cntE, 1);
            if (idx < ECAP) sh.eIdx[idx] = (uint32_t)e.tie;
        }
    }
    __syncthreads();
    const int need = sh.krem;
    const int nG = K - need;
    if (sh.cntE <= ECAP) {
        const int ce = sh.cntE;
        if (tid < ce) {
            uint32_t my = sh.eIdx[tid];
            int rank = 0;
            for (int j = 0; j < ce; ++j) rank += (sh.eIdx[j] < my);
            if (rank < need) { sh.candKey[nG + rank] = thr; sh.candIdx[nG + rank] = (int)my; }
        }
    } else {
        if (tid == 0) sh.flast = -1;
        __syncthreads();
        for (int t = 0; t < need; ++t) {
            if (tid == 0) sh.rmin = 0x7FFFFFFF;
            __syncthreads();
            const int fl = sh.flast;
            int lmin = 0x7FFFFFFF;
            for (int i = tid; i < N; i += 256) {
                KT e = get(i);
                if (e.key == thr && e.tie > fl) lmin = min(lmin, e.tie);
            }
            atomicMin(&sh.rmin, lmin);
            __syncthreads();
            if (tid == 0) { sh.candKey[nG + t] = thr; sh.candIdx[nG + t] = sh.rmin; sh.flast = sh.rmin; }
            __syncthreads();
        }
    }
    __syncthreads();
    if (tid < K) {
        uint32_t mk = sh.candKey[tid]; int mi = sh.candIdx[tid];
        int rank = 0;
        for (int j = 0; j < K; ++j) {
            uint32_t kj = sh.candKey[j]; int ij = sh.candIdx[j];
            rank += (kj > mk) || (kj == mk && ij < mi);
        }
        sh.sKey[rank] = mk; sh.sIdx[rank] = mi;
    }
    __syncthreads();
    return Ksel;
}

// ---------- kernel 1: coalesced scan + LDS aggregation + bulk reservation ----
__global__ __launch_bounds__(256) void cand_scan(const float4* __restrict__ predv,
                                                 uint2* __restrict__ cand,
                                                 int* __restrict__ cnt) {
    __shared__ uint2 buck[NCLS][LCAP];
    __shared__ int lcnt[NCLS];
    __shared__ int gbase[NCLS];

    const int tid = threadIdx.x;
    const int chunk = (TOTF4 + NBLK - 1) / NBLK;
    int s = blockIdx.x * chunk;
    int e = s + chunk;
    if (e > TOTF4) e = TOTF4;
    if (s >= e) return;

    // iterate over batch segments within [s, e)
    int segS = s;
    while (segS < e) {
        const int b = segS / BATF4;
        int segE = (b + 1) * BATF4;
        if (segE > e) segE = e;

        for (int j = tid; j < NCLS; j += 256) lcnt[j] = 0;
        __syncthreads();

        for (int v = segS + tid; v < segE; v += 256) {
            float4 p = predv[v];
            uint32_t q = (uint32_t)v / 21u;
            uint32_t j = (uint32_t)v - q * 21u;
            if (j == 0u) continue;
            bool p0 = p.x > THRL, p1 = p.y > THRL, p2 = p.z > THRL, p3 = p.w > THRL;
            if (!(p0 | p1 | p2 | p3)) continue;
            uint32_t row = q - (uint32_t)b * (uint32_t)NANCH;
            int cbase = ((int)j - 1) * 4;
            float vv[4] = {p.x, p.y, p.z, p.w};
            bool pp[4] = {p0, p1, p2, p3};
#pragma unroll
            for (int k = 0; k < 4; ++k) {
                if (pp[k]) {
                    int c = cbase + k;
                    uint32_t key = f2key(sigm(vv[k]));
                    int slot = atomicAdd(&lcnt[c], 1);
                    if (slot < LCAP) {
                        buck[c][slot] = make_uint2(key, row);
                    } else {            // rare overflow: direct global path
                        int bc = b * NCLS + c;
                        int gs = atomicAdd(&cnt[bc], 1);
                        if (gs < CAP) cand[(size_t)bc * CAP + gs] = make_uint2(key, row);
                    }
                }
            }
        }
        __syncthreads();

        // bulk reservation: one global atomic per (block, class with candidates)
        if (tid < NCLS) {
            int lc = lcnt[tid];
            if (lc > LCAP) lc = LCAP;
            gbase[tid] = (lc > 0) ? atomicAdd(&cnt[b * NCLS + tid], lc) : 0;
        }
        __syncthreads();

        // cooperative copy LDS buckets -> global candidate lists
        for (int x = tid; x < NCLS * LCAP; x += 256) {
            int c = x >> 6;          // LCAP = 64
            int k = x & (LCAP - 1);
            int lc = lcnt[c];
            if (lc > LCAP) lc = LCAP;
            if (k < lc) {
                int gs = gbase[c] + k;
                if (gs < CAP)
                    cand[(size_t)(b * NCLS + c) * CAP + gs] = buck[c][k];
            }
        }
        __syncthreads();
        segS = segE;
    }
}

// ---------- kernel 2: per-(b,c) exact top-100 + wave NMS ---------------------
__global__ __launch_bounds__(256) void nms_sel(const float* __restrict__ pred,
                                               const uint2* __restrict__ cand,
                                               const int* __restrict__ cnt,
                                               float* __restrict__ cls_boxes,
                                               uint32_t* __restrict__ posKey,
                                               uint32_t* __restrict__ posFlat,
                                               int* __restrict__ posCnt,
                                               DimsTable dt) {
    __shared__ SelSh sh;
    const int c = blockIdx.x;
    const int b = blockIdx.y;
    const int tid = threadIdx.x;
    const int bc = b * NCLS + c;
    const int n = cnt[bc];

    if (n >= KSEL && n <= CAP) {
        const uint2* src = cand + (size_t)bc * CAP;
        auto g = [src](int i) { uint2 p = src[i]; KT e; e.key = p.x; e.tie = (int)p.y; return e; };
        block_select(g, n, KSEL, sh);
    } else {
        // exact fallback: full strided scan (never taken on this data)
        const float* src = pred + (size_t)b * NANCH * PREDC + 4 + c;
        auto g = [src](int i) { KT e; e.key = f2key(sigm(src[(size_t)i * PREDC])); e.tie = i; return e; };
        block_select(g, NANCH, KSEL, sh);
    }

    if (tid < 64) {
        const int l = tid;
        uint32_t key0 = sh.sKey[l]; int n0 = sh.sIdx[l];
        float4 pv0 = reinterpret_cast<const float4*>(pred)[((size_t)b * NANCH + n0) * (PREDC / 4) + 0];
        float b0[4]; decode_box(pv0, n0, dt, b0);
        float area0 = __fmul_rn(__fsub_rn(b0[2], b0[0]), __fsub_rn(b0[3], b0[1]));
        int k0 = key2f(key0) > 0.05f;

        const bool has1 = (l + 64) < KSEL;
        uint32_t key1 = 0; int n1 = 0;
        float b1[4] = {0.f, 0.f, 0.f, 0.f}; float area1 = 0.f; int k1 = 0;
        if (has1) {
            key1 = sh.sKey[l + 64]; n1 = sh.sIdx[l + 64];
            float4 pv1 = reinterpret_cast<const float4*>(pred)[((size_t)b * NANCH + n1) * (PREDC / 4) + 0];
            decode_box(pv1, n1, dt, b1);
            area1 = __fmul_rn(__fsub_rn(b1[2], b1[0]), __fsub_rn(b1[3], b1[1]));
            k1 = key2f(key1) > 0.05f;
        }

        for (int i = 0; i < KSEL; ++i) {
            int kk; float c0, c1, c2, c3, ca;
            if (i < 64) { kk = k0; c0 = b0[0]; c1 = b0[1]; c2 = b0[2]; c3 = b0[3]; ca = area0; }
            else        { kk = k1; c0 = b1[0]; c1 = b1[1]; c2 = b1[2]; c3 = b1[3]; ca = area1; }
            const int sl = i & 63;
            int ki = __shfl(kk, sl);
            if (ki) {
                float ix0 = __shfl(c0, sl), iy0 = __shfl(c1, sl);
                float ix1 = __shfl(c2, sl), iy1 = __shfl(c3, sl);
                float ia  = __shfl(ca, sl);
                if (k0 && l > i) {
                    float x1 = fmaxf(ix0, b0[0]), y1 = fmaxf(iy0, b0[1]);
                    float x2 = fminf(ix1, b0[2]), y2 = fminf(iy1, b0[3]);
                    float iw = fmaxf(__fsub_rn(x2, x1), 0.0f);
                    float ih = fmaxf(__fsub_rn(y2, y1), 0.0f);
                    float inter = __fmul_rn(iw, ih);
                    float uni = __fsub_rn(__fadd_rn(ia, area0), inter);
                    if (__fdiv_rn(inter, fmaxf(uni, 1e-8f)) > 0.5f) k0 = 0;
                }
                if (k1 && (l + 64) > i) {
                    float x1 = fmaxf(ix0, b1[0]), y1 = fmaxf(iy0, b1[1]);
                    float x2 = fminf(ix1, b1[2]), y2 = fminf(iy1, b1[3]);
                    float iw = fmaxf(__fsub_rn(x2, x1), 0.0f);
                    float ih = fmaxf(__fsub_rn(y2, y1), 0.0f);
                    float inter = __fmul_rn(iw, ih);
                    float uni = __fsub_rn(__fadd_rn(ia, area1), inter);
                    if (__fdiv_rn(inter, fmaxf(uni, 1e-8f)) > 0.5f) k1 = 0;
                }
            }
        }

        reinterpret_cast<float4*>(cls_boxes)[(size_t)b * NFLAT + c * KSEL + l] =
            make_float4(b0[0], b0[1], b0[2], b0[3]);
        if (has1)
            reinterpret_cast<float4*>(cls_boxes)[(size_t)b * NFLAT + c * KSEL + l + 64] =
                make_float4(b1[0], b1[1], b1[2], b1[3]);

        unsigned long long m0 = __ballot(k0);
        unsigned long long m1 = __ballot(k1);
        int tot = __popcll(m0) + __popcll(m1);
        int base;
        if (l == 0) base = atomicAdd(&posCnt[b], tot);
        base = __shfl(base, 0);
        if (k0) {
            int off = __popcll(m0 & ((1ull << l) - 1));
            posKey[(size_t)b * NFLAT + base + off] = key0;
            posFlat[(size_t)b * NFLAT + base + off] = (uint32_t)(c * KSEL + l);
        }
        if (k1) {
            int off = __popcll(m0) + __popcll(m1 & ((1ull << l) - 1));
            posKey[(size_t)b * NFLAT + base + off] = key1;
            posFlat[(size_t)b * NFLAT + base + off] = (uint32_t)(c * KSEL + l + 64);
        }
    }
}

// ---------- kernel 3: per-batch final top-100 over compacted positives -------
__global__ __launch_bounds__(256) void final_sel(const float* __restrict__ cls_boxes,
                                                 const uint32_t* __restrict__ posKey,
                                                 const uint32_t* __restrict__ posFlat,
                                                 const int* __restrict__ posCnt,
                                                 float* __restrict__ out) {
    __shared__ SelSh sh;
    const int b = blockIdx.x;
    const int tid = threadIdx.x;
    int m = posCnt[b];
    if (m > NFLAT) m = NFLAT;
    const uint32_t* pk = posKey + (size_t)b * NFLAT;
    const uint32_t* pf = posFlat + (size_t)b * NFLAT;
    auto g = [pk, pf](int i) { KT e; e.key = pk[i]; e.tie = (int)pf[i]; return e; };
    int K = block_select(g, m, KSEL, sh);
    if (tid < KSEL) {
        float4 ob = make_float4(0.f, 0.f, 0.f, 0.f);
        float sv = 0.f, cv = 0.f;
        if (tid < K) {
            sv = key2f(sh.sKey[tid]);
            int flat = sh.sIdx[tid];
            ob = reinterpret_cast<const float4*>(cls_boxes)[(size_t)b * NFLAT + flat];
            cv = (float)(flat / KSEL);
        }
        reinterpret_cast<float4*>(out)[(size_t)b * KSEL + tid] = ob;
        out[NB * KSEL * 4 + b * KSEL + tid] = sv;
        out[NB * KSEL * 5 + b * KSEL + tid] = cv;
    }
    if (tid == 0) out[NB * KSEL * 6 + b] = (float)K;
}

// ---------- host launcher ----------------------------------------------------
extern "C" void kernel_launch(void* const* d_in, const int* in_sizes, int n_in,
                              void* d_out, int out_size, void* d_ws, size_t ws_size,
                              hipStream_t stream) {
    const float* pred = (const float*)d_in[1];
    float* out = (float*)d_out;

    DimsTable dt;
    const double areasd[5] = {1024.0, 4096.0, 16384.0, 65536.0, 262144.0};
    const double ratios[3] = {0.5, 1.0, 2.0};
    const double scales[3] = {1.0, pow(2.0, 1.0 / 3.0), pow(2.0, 2.0 / 3.0)};
    for (int l = 0; l < 5; ++l)
        for (int ri = 0; ri < 3; ++ri) {
            double ah = sqrt(areasd[l] / ratios[ri]);
            double aw = areasd[l] / ah;
            for (int si = 0; si < 3; ++si) {
                dt.d[l][ri * 3 + si][0] = (float)(aw * scales[si]);
                dt.d[l][ri * 3 + si][1] = (float)(ah * scales[si]);
            }
        }

    // workspace layout
    char* wsb = (char*)d_ws;
    int* cnt = (int*)wsb;                       // [640]
    int* posCnt = cnt + NB * NCLS;              // [8]
    uint2* cand = (uint2*)(wsb + 4096);         // [640][CAP]
    float* cls_boxes = (float*)((char*)cand + (size_t)NB * NCLS * CAP * 8);  // [8][8000][4]
    uint32_t* posKey = (uint32_t*)(cls_boxes + (size_t)NB * NFLAT * 4);      // [8][8000]
    uint32_t* posFlat = posKey + (size_t)NB * NFLAT;                          // [8][8000]

    (void)hipMemsetAsync(d_ws, 0, 4096, stream);

    cand_scan<<<NBLK, 256, 0, stream>>>(reinterpret_cast<const float4*>(pred),
                                        cand, cnt);

    dim3 gb(NCLS, NB);
    nms_sel<<<gb, 256, 0, stream>>>(pred, cand, cnt, cls_boxes, posKey, posFlat,
                                    posCnt, dt);

    final_sel<<<NB, 256, 0, stream>>>(cls_boxes, posKey, posFlat, posCnt, out);
}